// Round 3
// baseline (849.190 us; speedup 1.0000x reference)
//
#include <hip/hip_runtime.h>

typedef __attribute__((ext_vector_type(8))) short bf16x8;
typedef __attribute__((ext_vector_type(4))) float f32x4;

#define NROWS   65536
#define NSLICE  8
#define SLICESZ 4160
#define SETSZ   (NSLICE*SLICESZ)   // 33280 floats per iteration set
#define EPSV    1e-8f

// ---- ws layout (float offsets) ----
#define WS_DEC   0
#define WS_LOSS  1
#define WS_SETS  16                          // 9 sets (iters 0..8 write)
#define WS_X2    (WS_SETS + 9*SETSZ)         // 299536
#define WS_ENCB  (WS_X2 + NROWS)             // 365072 (16B aligned: /4 ok)
#define WS_EBF   (WS_ENCB + 2097152)         // encBfrag
#define WS_END   (WS_EBF + 2097152)          // ~18.3 MB

static __device__ __forceinline__ unsigned short f2bf(float f) {
    union { float f; unsigned u; } v; v.f = f;
    unsigned u = v.u + 0x7fffu + ((v.u >> 16) & 1u);
    return (unsigned short)(u >> 16);
}
static __device__ __forceinline__ float bf2f(unsigned short h) {
    union { unsigned u; float f; } v; v.u = ((unsigned)h) << 16; return v.f;
}
static __device__ __forceinline__ uint4 pack8(const unsigned short* h) {
    uint4 o;
    o.x = h[0] | ((unsigned)h[1] << 16);
    o.y = h[2] | ((unsigned)h[3] << 16);
    o.z = h[4] | ((unsigned)h[5] << 16);
    o.w = h[6] | ((unsigned)h[7] << 16);
    return o;
}

// ---------------------------------------------------------------------------
// Decoder loss. 4096 blocks x 256 -> exactly 8 float4-pairs per thread, all
// loads issued as one batch (16 KB in flight/wave) + 4 independent acc chains.
// ---------------------------------------------------------------------------
__global__ __launch_bounds__(256, 4) void decoder_loss_kernel(
    const float* __restrict__ X, const float* __restrict__ Dec,
    float* __restrict__ out_sum)
{
    const int stride = 4096 * 256;
    int i = blockIdx.x * 256 + threadIdx.x;
    const f32x4* X4 = (const f32x4*)X;
    const f32x4* D4 = (const f32x4*)Dec;
    f32x4 va[8], vb[8];
    #pragma unroll
    for (int u = 0; u < 8; ++u) {
        va[u] = X4[i + u * stride];
        vb[u] = D4[i + u * stride];
    }
    float s0 = 0.f, s1 = 0.f, s2 = 0.f, s3 = 0.f;
    #pragma unroll
    for (int u = 0; u < 8; ++u) {
        f32x4 d = va[u] - vb[u];
        s0 = fmaf(d.x, d.x, s0);
        s1 = fmaf(d.y, d.y, s1);
        s2 = fmaf(d.z, d.z, s2);
        s3 = fmaf(d.w, d.w, s3);
    }
    float s = (s0 + s1) + (s2 + s3);
    #pragma unroll
    for (int off = 32; off; off >>= 1) s += __shfl_down(s, off, 64);
    __shared__ float red[4];
    if ((threadIdx.x & 63) == 0) red[threadIdx.x >> 6] = s;
    __syncthreads();
    if (threadIdx.x == 0) atomicAdd(out_sum, red[0] + red[1] + red[2] + red[3]);
}

// ---------------------------------------------------------------------------
// prep0: enc f32 -> encB (bf16 row-major), encBfrag (phase-2 B fragment
// order), x2[row] = |bf16(enc_row)|^2.  Grid 1024 x 256, 64 rows/block.
// ---------------------------------------------------------------------------
__global__ __launch_bounds__(256) void prep0(
    const float* __restrict__ enc, unsigned* __restrict__ encB,
    uint4* __restrict__ encBfrag, float* __restrict__ x2)
{
    __shared__ unsigned short L[64 * 64];
    int t = threadIdx.x;
    int rl = t >> 2, part = t & 3;
    int row = blockIdx.x * 64 + rl;
    const float4* src = (const float4*)(enc + (size_t)row * 64 + part * 16);
    unsigned short hv[16];
    float ss = 0.f;
    #pragma unroll
    for (int i = 0; i < 4; ++i) {
        float4 v = src[i];
        unsigned short a = f2bf(v.x), b = f2bf(v.y), c = f2bf(v.z), d = f2bf(v.w);
        hv[i*4+0] = a; hv[i*4+1] = b; hv[i*4+2] = c; hv[i*4+3] = d;
        float fa = bf2f(a), fb = bf2f(b), fc = bf2f(c), fd = bf2f(d);
        ss = fmaf(fa, fa, fmaf(fb, fb, fmaf(fc, fc, fmaf(fd, fd, ss))));
    }
    unsigned* dst = encB + ((size_t)row * 64 + part * 16) / 2;
    #pragma unroll
    for (int i = 0; i < 8; ++i) dst[i] = (unsigned)hv[2*i] | ((unsigned)hv[2*i+1] << 16);
    #pragma unroll
    for (int i = 0; i < 16; ++i) L[rl * 64 + part * 16 + i] = hv[i];
    ss += __shfl_xor(ss, 1, 64);
    ss += __shfl_xor(ss, 2, 64);
    if (part == 0) x2[row] = ss;
    __syncthreads();
    for (int e = t; e < 512; e += 256) {
        int rbl = e >> 8, dt = (e >> 6) & 3, lane = e & 63;
        int q = lane >> 4, c = lane & 15;
        unsigned short hw[8];
        #pragma unroll
        for (int j = 0; j < 8; ++j)
            hw[j] = L[(rbl * 32 + q * 8 + j) * 64 + dt * 16 + c];
        encBfrag[(size_t)blockIdx.x * 512 + e] = pack8(hw);
    }
}

// ---------------------------------------------------------------------------
// Fused k-means iteration (prepC folded in). Grid 256 x 512 (8 waves),
// 256 rows/block, 32 rows/wave.
//  prologue: rebuild C from prev set (or enc if mode 0) in LDS, c2, frags
//  phase 1 : S = enc@C^T (mfma 16x16x32), softmax in C-layout registers
//  phase 2 : r^T@enc (r frags ARE the A operand), LDS reduce, sliced atomics
//  mode 2  : loss only
// ---------------------------------------------------------------------------
__global__ __launch_bounds__(512, 2) void kmeans_main(
    const bf16x8* __restrict__ encB8, const bf16x8* __restrict__ encBfrag8,
    const float* __restrict__ enc, const float* __restrict__ prev_set,
    float* __restrict__ cur_set, const float* __restrict__ x2,
    float* __restrict__ loss_sum, int mode)
{
    __shared__ float CfCnew[4096];          // f32 C (prologue) / Cnew (epilogue)
    __shared__ unsigned short CsBf[4096];   // bf16 C
    __shared__ float rsl[64];
    __shared__ float c2L[64];
    __shared__ float rsumL[64];
    __shared__ float lred[8];

    int t = threadIdx.x;
    int wave = t >> 6, lane = t & 63, q = lane >> 4, c = lane & 15;

    // ---- prologue: build C ----
    if (t < 64) {
        float v = 0.f;
        if (mode != 0) {
            #pragma unroll
            for (int sl = 0; sl < NSLICE; ++sl)
                v += prev_set[sl * SLICESZ + 4096 + t];
        }
        rsl[t] = v + EPSV;
    }
    __syncthreads();
    #pragma unroll
    for (int j = 0; j < 8; ++j) {
        int idx = j * 512 + t;
        float v;
        if (mode == 0) v = enc[idx];
        else {
            float s = 0.f;
            #pragma unroll
            for (int sl = 0; sl < NSLICE; ++sl) s += prev_set[sl * SLICESZ + idx];
            v = s / rsl[idx >> 6];
        }
        CfCnew[idx] = v;
        CsBf[idx] = f2bf(v);
    }
    __syncthreads();
    if (t < 64) {
        float s = 0.f;
        #pragma unroll
        for (int d = 0; d < 64; ++d) { float v = CfCnew[t * 64 + d]; s = fmaf(v, v, s); }
        c2L[t] = s;
    }
    bf16x8 bfr[2][4];
    #pragma unroll
    for (int kk = 0; kk < 2; ++kk)
        #pragma unroll
        for (int nt = 0; nt < 4; ++nt)
            bfr[kk][nt] = *(const bf16x8*)&CsBf[(nt * 16 + c) * 64 + kk * 32 + q * 8];
    __syncthreads();
    float c2f[4];
    #pragma unroll
    for (int nt = 0; nt < 4; ++nt) c2f[nt] = c2L[nt * 16 + c];
    for (int i = t; i < 4096; i += 512) CfCnew[i] = 0.f;   // now Cnew accumulator
    if (t < 64) rsumL[t] = 0.f;
    __syncthreads();

    // ---- phase 1 + softmax ----
    int R0 = blockIdx.x * 256 + wave * 32;
    const f32x4 z4 = {0.f, 0.f, 0.f, 0.f};
    f32x4 cacc[16];
    #pragma unroll
    for (int i = 0; i < 16; ++i) cacc[i] = z4;
    float rs[4] = {0.f, 0.f, 0.f, 0.f};
    float lossacc = 0.f;
    bf16x8 a2f[4];

    #pragma unroll
    for (int sub = 0; sub < 2; ++sub) {
        int arow = R0 + 8 * (c >> 2) + sub * 4 + (c & 3);
        const bf16x8* ap = encB8 + (size_t)arow * 8 + q;
        bf16x8 a0 = ap[0], a1 = ap[4];
        f32x4 accf[4];
        #pragma unroll
        for (int nt = 0; nt < 4; ++nt) {
            f32x4 s = __builtin_amdgcn_mfma_f32_16x16x32_bf16(a0, bfr[0][nt], z4, 0, 0, 0);
            accf[nt]  = __builtin_amdgcn_mfma_f32_16x16x32_bf16(a1, bfr[1][nt], s,  0, 0, 0);
        }
        #pragma unroll
        for (int reg = 0; reg < 4; ++reg) {
            int row = R0 + 8 * q + sub * 4 + reg;
            float x2r = x2[row];
            float d2[4], mn = 3.4e38f;
            #pragma unroll
            for (int nt = 0; nt < 4; ++nt) {
                float v = fmaxf(x2r + c2f[nt] - 2.f * accf[nt][reg], 0.f);
                d2[nt] = v; mn = fminf(mn, v);
            }
            mn = fminf(mn, __shfl_xor(mn, 1, 64));
            mn = fminf(mn, __shfl_xor(mn, 2, 64));
            mn = fminf(mn, __shfl_xor(mn, 4, 64));
            mn = fminf(mn, __shfl_xor(mn, 8, 64));
            float e[4], s = 0.f, swd = 0.f;
            #pragma unroll
            for (int nt = 0; nt < 4; ++nt) {
                float ev = __expf(mn - d2[nt]);
                e[nt] = ev; s += ev; swd = fmaf(ev, d2[nt], swd);
            }
            s   += __shfl_xor(s, 1, 64);   swd += __shfl_xor(swd, 1, 64);
            s   += __shfl_xor(s, 2, 64);   swd += __shfl_xor(swd, 2, 64);
            s   += __shfl_xor(s, 4, 64);   swd += __shfl_xor(swd, 4, 64);
            s   += __shfl_xor(s, 8, 64);   swd += __shfl_xor(swd, 8, 64);
            float inv = 1.f / s;
            if (mode == 2 && c == 0) lossacc += swd * inv;
            #pragma unroll
            for (int nt = 0; nt < 4; ++nt) {
                float rv = e[nt] * inv;
                rs[nt] += rv;
                a2f[nt][sub * 4 + reg] = (short)f2bf(rv);
            }
        }
    }

    if (mode != 2) {
        // ---- phase 2: Cnew += r^T @ enc ----
        int rb = blockIdx.x * 8 + wave;
        #pragma unroll
        for (int dt = 0; dt < 4; ++dt) {
            bf16x8 b2 = encBfrag8[(size_t)(rb * 4 + dt) * 64 + lane];
            #pragma unroll
            for (int mt = 0; mt < 4; ++mt)
                cacc[mt * 4 + dt] = __builtin_amdgcn_mfma_f32_16x16x32_bf16(
                    a2f[mt], b2, cacc[mt * 4 + dt], 0, 0, 0);
        }
        #pragma unroll
        for (int mt = 0; mt < 4; ++mt)
            #pragma unroll
            for (int dt = 0; dt < 4; ++dt)
                #pragma unroll
                for (int reg = 0; reg < 4; ++reg)
                    atomicAdd(&CfCnew[(mt * 16 + q * 4 + reg) * 64 + dt * 16 + c],
                              cacc[mt * 4 + dt][reg]);
        #pragma unroll
        for (int nt = 0; nt < 4; ++nt) {
            float v = rs[nt];
            v += __shfl_xor(v, 16, 64);
            v += __shfl_xor(v, 32, 64);
            if (q == 0) atomicAdd(&rsumL[nt * 16 + c], v);
        }
        __syncthreads();
        float* slice = cur_set + (size_t)(blockIdx.x & (NSLICE - 1)) * SLICESZ;
        for (int i = t; i < 4096; i += 512) atomicAdd(&slice[i], CfCnew[i]);
        if (t < 64) atomicAdd(&slice[4096 + t], rsumL[t]);
    } else {
        #pragma unroll
        for (int off = 32; off; off >>= 1) lossacc += __shfl_down(lossacc, off, 64);
        if (lane == 0) lred[wave] = lossacc;
        __syncthreads();
        if (t < 8) {
            float v = lred[t];
            v += __shfl_down(v, 4, 64);
            v += __shfl_down(v, 2, 64);
            v += __shfl_down(v, 1, 64);
            if (t == 0) atomicAdd(loss_sum, v);
        }
    }
}

// ---------------------------------------------------------------------------
__global__ void finalize_kernel(const float* __restrict__ dec_sum,
                                const float* __restrict__ loss_sum,
                                float* __restrict__ out)
{
    out[0] = dec_sum[0] * (1.f / (65536.f * 512.f))
           + 0.001f * (loss_sum[0] * (1.f / 65536.f));
}

// ---------------------------------------------------------------------------
extern "C" void kernel_launch(void* const* d_in, const int* in_sizes, int n_in,
                              void* d_out, int out_size, void* d_ws, size_t ws_size,
                              hipStream_t stream)
{
    const float* X   = (const float*)d_in[0];
    const float* enc = (const float*)d_in[1];
    const float* dec = (const float*)d_in[2];

    float* ws = (float*)d_ws;
    float* dec_sum  = ws + WS_DEC;
    float* loss_sum = ws + WS_LOSS;
    float* sets = ws + WS_SETS;
    float* x2   = ws + WS_X2;
    unsigned* encB  = (unsigned*)(ws + WS_ENCB);
    uint4* encBfrag = (uint4*)(ws + WS_EBF);

    // zero sums + all 9 accumulator sets (~1.2 MB), once
    hipMemsetAsync(d_ws, 0, (size_t)WS_X2 * sizeof(float), stream);

    decoder_loss_kernel<<<dim3(4096), dim3(256), 0, stream>>>(X, dec, dec_sum);
    prep0<<<dim3(1024), dim3(256), 0, stream>>>(enc, encB, encBfrag, x2);

    const bf16x8* encB8 = (const bf16x8*)encB;
    const bf16x8* eBf8  = (const bf16x8*)encBfrag;

    for (int it = 0; it < 10; ++it) {
        int mode = (it == 0) ? 0 : ((it == 9) ? 2 : 1);
        const float* prev = (it == 0) ? sets : sets + (size_t)(it - 1) * SETSZ;
        float* cur = (it < 9) ? sets + (size_t)it * SETSZ : sets;
        kmeans_main<<<dim3(256), dim3(512), 0, stream>>>(
            encB8, eBf8, enc, prev, cur, x2, loss_sum, mode);
    }
    finalize_kernel<<<1, 1, 0, stream>>>(dec_sum, loss_sum, (float*)d_out);
}

// Round 4
// 490.147 us; speedup vs baseline: 1.7325x; 1.7325x over previous
//
#include <hip/hip_runtime.h>

typedef __attribute__((ext_vector_type(8))) short bf16x8;
typedef __attribute__((ext_vector_type(4))) float f32x4;

#define NROWS   65536
#define NSLICE  8
#define SLICESZ 4160
#define SETSZ   (NSLICE*SLICESZ)   // 33280 floats per iteration set
#define EPSV    1e-8f
#define RPITCH  264                 // rLT row pitch in halfwords (+8 pad)

// ---- ws layout (float offsets) ----
#define WS_DEC   0
#define WS_LOSS  1
#define WS_SETS  16                          // 9 sets (iters 0..8 write)
#define WS_X2    (WS_SETS + 9*SETSZ)         // 299536
#define WS_ENCB  (WS_X2 + NROWS)             // 365072
#define WS_EBF   (WS_ENCB + 2097152)
#define WS_END   (WS_EBF + 2097152)          // ~18.3 MB

static __device__ __forceinline__ unsigned short f2bf(float f) {
    union { float f; unsigned u; } v; v.f = f;
    unsigned u = v.u + 0x7fffu + ((v.u >> 16) & 1u);
    return (unsigned short)(u >> 16);
}
static __device__ __forceinline__ float bf2f(unsigned short h) {
    union { unsigned u; float f; } v; v.u = ((unsigned)h) << 16; return v.f;
}
static __device__ __forceinline__ uint4 pack8(const unsigned short* h) {
    uint4 o;
    o.x = h[0] | ((unsigned)h[1] << 16);
    o.y = h[2] | ((unsigned)h[3] << 16);
    o.z = h[4] | ((unsigned)h[5] << 16);
    o.w = h[6] | ((unsigned)h[7] << 16);
    return o;
}

// ---------------------------------------------------------------------------
// Decoder loss: nontemporal streaming reads (don't pollute L2/L3 where the
// kmeans working set lives), 4 independent load pairs + 4 acc chains.
// ---------------------------------------------------------------------------
__global__ __launch_bounds__(256, 4) void decoder_loss_kernel(
    const float* __restrict__ X, const float* __restrict__ Dec,
    float* __restrict__ out_sum)
{
    const int stride = 8192 * 256;
    int i = blockIdx.x * 256 + threadIdx.x;
    const f32x4* X4 = (const f32x4*)X;
    const f32x4* D4 = (const f32x4*)Dec;
    f32x4 va[4], vb[4];
    #pragma unroll
    for (int u = 0; u < 4; ++u) va[u] = __builtin_nontemporal_load(&X4[i + u * stride]);
    #pragma unroll
    for (int u = 0; u < 4; ++u) vb[u] = __builtin_nontemporal_load(&D4[i + u * stride]);
    float s0 = 0.f, s1 = 0.f, s2 = 0.f, s3 = 0.f;
    #pragma unroll
    for (int u = 0; u < 4; ++u) {
        f32x4 d = va[u] - vb[u];
        s0 = fmaf(d.x, d.x, s0);
        s1 = fmaf(d.y, d.y, s1);
        s2 = fmaf(d.z, d.z, s2);
        s3 = fmaf(d.w, d.w, s3);
    }
    float s = (s0 + s1) + (s2 + s3);
    #pragma unroll
    for (int off = 32; off; off >>= 1) s += __shfl_down(s, off, 64);
    __shared__ float red[4];
    if ((threadIdx.x & 63) == 0) red[threadIdx.x >> 6] = s;
    __syncthreads();
    if (threadIdx.x == 0) atomicAdd(out_sum, red[0] + red[1] + red[2] + red[3]);
}

// ---------------------------------------------------------------------------
// prep0: enc f32 -> encB (bf16 row-major), encBfrag (phase-2 B fragment
// order), x2[row] = |bf16(enc_row)|^2.  Grid 1024 x 256, 64 rows/block.
// ---------------------------------------------------------------------------
__global__ __launch_bounds__(256) void prep0(
    const float* __restrict__ enc, unsigned* __restrict__ encB,
    uint4* __restrict__ encBfrag, float* __restrict__ x2)
{
    __shared__ unsigned short L[64 * 64];
    int t = threadIdx.x;
    int rl = t >> 2, part = t & 3;
    int row = blockIdx.x * 64 + rl;
    const float4* src = (const float4*)(enc + (size_t)row * 64 + part * 16);
    unsigned short hv[16];
    float ss = 0.f;
    #pragma unroll
    for (int i = 0; i < 4; ++i) {
        float4 v = src[i];
        unsigned short a = f2bf(v.x), b = f2bf(v.y), c = f2bf(v.z), d = f2bf(v.w);
        hv[i*4+0] = a; hv[i*4+1] = b; hv[i*4+2] = c; hv[i*4+3] = d;
        float fa = bf2f(a), fb = bf2f(b), fc = bf2f(c), fd = bf2f(d);
        ss = fmaf(fa, fa, fmaf(fb, fb, fmaf(fc, fc, fmaf(fd, fd, ss))));
    }
    unsigned* dst = encB + ((size_t)row * 64 + part * 16) / 2;
    #pragma unroll
    for (int i = 0; i < 8; ++i) dst[i] = (unsigned)hv[2*i] | ((unsigned)hv[2*i+1] << 16);
    #pragma unroll
    for (int i = 0; i < 16; ++i) L[rl * 64 + part * 16 + i] = hv[i];
    ss += __shfl_xor(ss, 1, 64);
    ss += __shfl_xor(ss, 2, 64);
    if (part == 0) x2[row] = ss;
    __syncthreads();
    for (int e = t; e < 512; e += 256) {
        int rbl = e >> 8, dt = (e >> 6) & 3, lane = e & 63;
        int q = lane >> 4, c = lane & 15;
        unsigned short hw[8];
        #pragma unroll
        for (int j = 0; j < 8; ++j)
            hw[j] = L[(rbl * 32 + q * 8 + j) * 64 + dt * 16 + c];
        encBfrag[(size_t)blockIdx.x * 512 + e] = pack8(hw);
    }
}

// ---------------------------------------------------------------------------
// Fused k-means iteration, wave-owned-output-tile structure.
// Grid 256 x 256 (4 waves), 256 rows/block (2 phase-1 passes of 128).
//  prologue: build C (bf16) from prev set / enc, c2 via shuffle reduce
//  phase 1 : S = enc@C^T (mfma), softmax, r frags -> LDS (transposed)
//  phase 2 : wave w owns k-rows mt=w: iterates 8 row-subtiles, 32 mfma,
//            flushes its 16x64 tile with global atomics (no LDS reduce)
// ---------------------------------------------------------------------------
__global__ __launch_bounds__(256, 3) void kmeans_main(
    const bf16x8* __restrict__ encB8, const bf16x8* __restrict__ encBfrag8,
    const float* __restrict__ enc, const float* __restrict__ prev_set,
    float* __restrict__ cur_set, const float* __restrict__ x2,
    float* __restrict__ loss_sum, int mode)
{
    __shared__ union {
        unsigned short CsBf[4096];        // prologue: bf16 C[k][d]
        unsigned short rLT[64 * RPITCH];  // phase 1/2: r^T  [k][row_local]
    } U;
    __shared__ float x2L[256];
    __shared__ float c2L[64];
    __shared__ float rslL[64];
    __shared__ float rsumL[64];
    __shared__ float lredL[4];

    const int t = threadIdx.x;
    const int wave = t >> 6, lane = t & 63, q = lane >> 4, c = lane & 15;
    const int blockR0 = blockIdx.x * 256;

    // ---- prologue ----
    x2L[t] = x2[blockR0 + t];
    if (t < 64) {
        rsumL[t] = 0.f;
        float v = 0.f;
        if (mode != 0) {
            #pragma unroll
            for (int sl = 0; sl < NSLICE; ++sl)
                v += prev_set[sl * SLICESZ + 4096 + t];
        }
        rslL[t] = 1.f / (v + EPSV);
    }
    __syncthreads();

    float c2part[4];
    #pragma unroll
    for (int j = 0; j < 4; ++j) {
        int v4 = t + j * 256;      // f32x4 index into C (1024 total)
        int row = v4 >> 4;
        float vx, vy, vz, vw;
        if (mode == 0) {
            f32x4 e = ((const f32x4*)enc)[v4];
            vx = e.x; vy = e.y; vz = e.z; vw = e.w;
        } else {
            float sx = 0.f, sy = 0.f, sz = 0.f, sw = 0.f;
            #pragma unroll
            for (int sl = 0; sl < NSLICE; ++sl) {
                f32x4 u = ((const f32x4*)(prev_set + (size_t)sl * SLICESZ))[v4];
                sx += u.x; sy += u.y; sz += u.z; sw += u.w;
            }
            float inv = rslL[row];
            vx = sx * inv; vy = sy * inv; vz = sz * inv; vw = sw * inv;
        }
        ushort4 h;
        h.x = f2bf(vx); h.y = f2bf(vy); h.z = f2bf(vz); h.w = f2bf(vw);
        ((ushort4*)U.CsBf)[v4] = h;
        float fx = bf2f(h.x), fy = bf2f(h.y), fz = bf2f(h.z), fw = bf2f(h.w);
        c2part[j] = fmaf(fx, fx, fmaf(fy, fy, fmaf(fz, fz, fw * fw)));
    }
    #pragma unroll
    for (int j = 0; j < 4; ++j) {
        float p = c2part[j];
        p += __shfl_xor(p, 1, 64); p += __shfl_xor(p, 2, 64);
        p += __shfl_xor(p, 4, 64); p += __shfl_xor(p, 8, 64);
        if ((lane & 15) == 0) c2L[j * 16 + (t >> 4)] = p;
    }
    __syncthreads();

    bf16x8 bfr[2][4];
    #pragma unroll
    for (int kk2 = 0; kk2 < 2; ++kk2)
        #pragma unroll
        for (int nt = 0; nt < 4; ++nt)
            bfr[kk2][nt] = *(const bf16x8*)&U.CsBf[(nt * 16 + c) * 64 + kk2 * 32 + q * 8];
    float c2f[4];
    #pragma unroll
    for (int nt = 0; nt < 4; ++nt) c2f[nt] = c2L[nt * 16 + c];
    __syncthreads();   // CsBf dead; U.rLT may now be written

    // ---- phase 1 (+softmax), 2 passes of 128 rows ----
    const f32x4 z4 = {0.f, 0.f, 0.f, 0.f};
    float rs[4] = {0.f, 0.f, 0.f, 0.f};
    float lossacc = 0.f;
    #pragma unroll
    for (int p = 0; p < 2; ++p) {
        bf16x8 a2f[4];
        #pragma unroll
        for (int sub = 0; sub < 2; ++sub) {
            int arow = blockR0 + p * 128 + wave * 32 + 8 * (c >> 2) + sub * 4 + (c & 3);
            const bf16x8* ap = encB8 + (size_t)arow * 8 + q;
            bf16x8 a0 = ap[0], a1 = ap[4];
            f32x4 accf[4];
            #pragma unroll
            for (int nt = 0; nt < 4; ++nt) {
                f32x4 s = __builtin_amdgcn_mfma_f32_16x16x32_bf16(a0, bfr[0][nt], z4, 0, 0, 0);
                accf[nt]  = __builtin_amdgcn_mfma_f32_16x16x32_bf16(a1, bfr[1][nt], s,  0, 0, 0);
            }
            #pragma unroll
            for (int reg = 0; reg < 4; ++reg) {
                int rloc = p * 128 + wave * 32 + 8 * q + sub * 4 + reg;
                float x2r = x2L[rloc];
                float d2[4], mn = 3.4e38f;
                #pragma unroll
                for (int nt = 0; nt < 4; ++nt) {
                    float v = fmaxf(x2r + c2f[nt] - 2.f * accf[nt][reg], 0.f);
                    d2[nt] = v; mn = fminf(mn, v);
                }
                mn = fminf(mn, __shfl_xor(mn, 1, 64));
                mn = fminf(mn, __shfl_xor(mn, 2, 64));
                mn = fminf(mn, __shfl_xor(mn, 4, 64));
                mn = fminf(mn, __shfl_xor(mn, 8, 64));
                float e[4], s = 0.f, swd = 0.f;
                #pragma unroll
                for (int nt = 0; nt < 4; ++nt) {
                    float ev = __expf(mn - d2[nt]);
                    e[nt] = ev; s += ev; swd = fmaf(ev, d2[nt], swd);
                }
                s   += __shfl_xor(s, 1, 64);   swd += __shfl_xor(swd, 1, 64);
                s   += __shfl_xor(s, 2, 64);   swd += __shfl_xor(swd, 2, 64);
                s   += __shfl_xor(s, 4, 64);   swd += __shfl_xor(swd, 4, 64);
                s   += __shfl_xor(s, 8, 64);   swd += __shfl_xor(swd, 8, 64);
                float inv = 1.f / s;
                if (mode == 2 && c == 0) lossacc += swd * inv;
                #pragma unroll
                for (int nt = 0; nt < 4; ++nt) {
                    float rv = e[nt] * inv;
                    rs[nt] += rv;
                    a2f[nt][sub * 4 + reg] = (short)f2bf(rv);
                }
            }
        }
        if (mode != 2) {
            #pragma unroll
            for (int nt = 0; nt < 4; ++nt)
                *(bf16x8*)&U.rLT[(nt * 16 + c) * RPITCH + p * 128 + wave * 32 + 8 * q] = a2f[nt];
        }
    }

    if (mode != 2) {
        #pragma unroll
        for (int nt = 0; nt < 4; ++nt) {
            float v = rs[nt];
            v += __shfl_xor(v, 16, 64);
            v += __shfl_xor(v, 32, 64);
            if (q == 0) atomicAdd(&rsumL[nt * 16 + c], v);
        }
        __syncthreads();   // rLT visible, rsumL complete

        // ---- phase 2: wave owns k-rows mt=wave, all 8 row-subtiles ----
        const int mt = wave;
        f32x4 cacc[4];
        #pragma unroll
        for (int dt = 0; dt < 4; ++dt) cacc[dt] = z4;
        #pragma unroll
        for (int kk = 0; kk < 8; ++kk) {
            bf16x8 aA = *(const bf16x8*)&U.rLT[(mt * 16 + c) * RPITCH + kk * 32 + q * 8];
            #pragma unroll
            for (int dt = 0; dt < 4; ++dt) {
                bf16x8 bB = encBfrag8[((size_t)(blockIdx.x * 8 + kk) * 4 + dt) * 64 + lane];
                cacc[dt] = __builtin_amdgcn_mfma_f32_16x16x32_bf16(aA, bB, cacc[dt], 0, 0, 0);
            }
        }
        float* slice = cur_set + (size_t)(blockIdx.x & (NSLICE - 1)) * SLICESZ;
        #pragma unroll
        for (int dt = 0; dt < 4; ++dt)
            #pragma unroll
            for (int reg = 0; reg < 4; ++reg)
                atomicAdd(&slice[(mt * 16 + q * 4 + reg) * 64 + dt * 16 + c],
                          cacc[dt][reg]);
        if (t < 64) atomicAdd(&slice[4096 + t], rsumL[t]);
    } else {
        #pragma unroll
        for (int off = 32; off; off >>= 1) lossacc += __shfl_down(lossacc, off, 64);
        if (lane == 0) lredL[wave] = lossacc;
        __syncthreads();
        if (t == 0) atomicAdd(loss_sum, lredL[0] + lredL[1] + lredL[2] + lredL[3]);
    }
}

// ---------------------------------------------------------------------------
__global__ void finalize_kernel(const float* __restrict__ dec_sum,
                                const float* __restrict__ loss_sum,
                                float* __restrict__ out)
{
    out[0] = dec_sum[0] * (1.f / (65536.f * 512.f))
           + 0.001f * (loss_sum[0] * (1.f / 65536.f));
}

// ---------------------------------------------------------------------------
extern "C" void kernel_launch(void* const* d_in, const int* in_sizes, int n_in,
                              void* d_out, int out_size, void* d_ws, size_t ws_size,
                              hipStream_t stream)
{
    const float* X   = (const float*)d_in[0];
    const float* enc = (const float*)d_in[1];
    const float* dec = (const float*)d_in[2];

    float* ws = (float*)d_ws;
    float* dec_sum  = ws + WS_DEC;
    float* loss_sum = ws + WS_LOSS;
    float* sets = ws + WS_SETS;
    float* x2   = ws + WS_X2;
    unsigned* encB  = (unsigned*)(ws + WS_ENCB);
    uint4* encBfrag = (uint4*)(ws + WS_EBF);

    hipMemsetAsync(d_ws, 0, (size_t)WS_X2 * sizeof(float), stream);

    decoder_loss_kernel<<<dim3(8192), dim3(256), 0, stream>>>(X, dec, dec_sum);
    prep0<<<dim3(1024), dim3(256), 0, stream>>>(enc, encB, encBfrag, x2);

    const bf16x8* encB8 = (const bf16x8*)encB;
    const bf16x8* eBf8  = (const bf16x8*)encBfrag;

    for (int it = 0; it < 10; ++it) {
        int mode = (it == 0) ? 0 : ((it == 9) ? 2 : 1);
        const float* prev = (it == 0) ? sets : sets + (size_t)(it - 1) * SETSZ;
        float* cur = (it < 9) ? sets + (size_t)it * SETSZ : sets;
        kmeans_main<<<dim3(256), dim3(256), 0, stream>>>(
            encB8, eBf8, enc, prev, cur, x2, loss_sum, mode);
    }
    finalize_kernel<<<1, 1, 0, stream>>>(dec_sum, loss_sum, (float*)d_out);
}